// Round 6
// baseline (552.715 us; speedup 1.0000x reference)
//
#include <hip/hip_runtime.h>
#include <math.h>

#define NN 50000
#define EE 800000
#define FF 64
#define HH 128
#define LL 4
#define GG 64
#define CC 10
#define TT 256     // table points per layer (8-bit index)
#define TTP 257    // +1 zero row at index 0 (sentinel); real rows 1..256
#define BD 64      // padded bucket capacity per dst
#define ABLK 1024  // phase-A part blocks
#define EPB 782    // edges per phase-A block
#define SEGC 192   // per (block,region) segment capacity
#define SUBB 96    // phase-B sub-blocks per region
#define SRW 6250   // dst region width (NN/8)

// prep kernel block ranges
#define PB_CVTW 8
#define PB_TAB ((TT / 16) * LL)      // 64
#define PB_CVTX (NN * FF / 4 / 256)  // 3125
#define PB_PART ABLK

#define SCB (8 * SUBB)   // 768 scatter blocks in the combined dispatch
#define GEMMB (NN / 16)  // 3125 gemm tiles

typedef unsigned short ushort_t;
typedef unsigned int uint_t;
typedef unsigned long long u64_t;

typedef short s8v __attribute__((ext_vector_type(8)));
typedef float f32x4 __attribute__((ext_vector_type(4)));

__device__ inline ushort_t f2bf(float f) {
  uint_t u = __float_as_uint(f);
  uint_t r = (u + 0x7FFFu + ((u >> 16) & 1u)) >> 16;
  return (ushort_t)r;
}
__device__ inline float bf1f(ushort_t v) { return __uint_as_float(((uint_t)v) << 16); }

// f16 helpers: (float)h * (float)h + f32acc lowers to v_fma_mix_f32 (no unpack).
__device__ inline ushort_t f2h(float f) {
  union { _Float16 h[2]; ushort_t us[2]; } c;
  c.h[0] = (_Float16)f;
  return c.us[0];
}
__device__ inline float h_lo(uint_t u) {
  union { uint_t w; _Float16 h[2]; } c; c.w = u; return (float)c.h[0];
}
__device__ inline float h_hi(uint_t u) {
  union { uint_t w; _Float16 h[2]; } c; c.w = u; return (float)c.h[1];
}

// ---------------- fused prep: cvt_w | build_tables | cvt_x | part_edges | gcnt+gsum ----------------
__global__ __launch_bounds__(256) void prep(
    const float* __restrict__ x, ushort_t* __restrict__ xb,
    const float* __restrict__ W1_0, const float* __restrict__ W1_rest,
    const float* __restrict__ W2, ushort_t* __restrict__ wt,
    const float* __restrict__ Wf1, const float* __restrict__ bf1,
    const float* __restrict__ Wf2, const float* __restrict__ bf2,
    ushort_t* __restrict__ tables,
    const int* __restrict__ dst, const int* __restrict__ src,
    const float* __restrict__ dist,
    uint_t* __restrict__ seg, int* __restrict__ segcnt, int* __restrict__ bcnt,
    const int* __restrict__ gid, int* __restrict__ gcnt, float* __restrict__ gsum) {
  __shared__ float rbf[16][HH];
  __shared__ float hid[16][HH];
  __shared__ int lcnt[8];
  int tid = threadIdx.x;
  int b = blockIdx.x;

  if (b < PB_CVTW) {
    int mid = b;
    const float* srcm; int K;
    if (mid == 0) { srcm = W1_0; K = FF; }
    else if (mid < 4) { srcm = W1_rest + (size_t)(mid - 1) * HH * HH; K = HH; }
    else { srcm = W2 + (size_t)(mid - 4) * HH * HH; K = HH; }
    ushort_t* dstm = wt + (size_t)mid * HH * HH;
    for (int idx = tid; idx < K * HH; idx += 256) {
      int k = idx >> 7, n = idx & 127;
      dstm[n * K + k] = f2bf(srcm[idx]);
    }
  } else if (b < PB_CVTW + PB_TAB) {
    int bb = b - PB_CVTW;
    int l = bb & 3;
    int tb = (bb >> 2) * 16;
    int j = tid & 127;
    float c = j * (1.0f / (HH - 1));
#pragma unroll
    for (int tt2 = 0; tt2 < 16; ++tt2) {
      float d = (tb + tt2) * (1.0f / (TT - 1));
      float dd = d - c;
      rbf[tt2][j] = expf(-10.0f * dd * dd);
    }
    __syncthreads();
    const float* W1f = Wf1 + (size_t)l * HH * HH;
    float s[16];
    float bb1 = bf1[l * HH + j];
#pragma unroll
    for (int tt2 = 0; tt2 < 16; ++tt2) s[tt2] = bb1;
    for (int k = 0; k < HH; ++k) {
      float wk = W1f[(size_t)k * HH + j];
#pragma unroll
      for (int tt2 = 0; tt2 < 16; ++tt2) s[tt2] += rbf[tt2][k] * wk;
    }
#pragma unroll
    for (int tt2 = 0; tt2 < 16; ++tt2)
      hid[tt2][j] = fmaxf(s[tt2], 0.f) + log1pf(expf(-fabsf(s[tt2]))) - 0.6931472f;
    __syncthreads();
    const float* W2f = Wf2 + (size_t)l * HH * HH;
    float bb2 = bf2[l * HH + j];
#pragma unroll
    for (int tt2 = 0; tt2 < 16; ++tt2) s[tt2] = bb2;
    for (int k = 0; k < HH; ++k) {
      float wk = W2f[(size_t)k * HH + j];
#pragma unroll
      for (int tt2 = 0; tt2 < 16; ++tt2) s[tt2] += hid[tt2][k] * wk;
    }
    if (tid < 128) {
      // rows shifted by +1: row 0 of each layer's table is the zero sentinel row
#pragma unroll
      for (int tt2 = 0; tt2 < 16; ++tt2)
        tables[((size_t)l * TTP + 1 + tb + tt2) * HH + j] = f2h(s[tt2]);
    }
  } else if (b < PB_CVTW + PB_TAB + PB_CVTX) {
    int i = (b - PB_CVTW - PB_TAB) * 256 + tid;
    const float4* x4 = (const float4*)x;
    float4 v = x4[i];
    union { ushort_t us[4]; u64_t u; } pk;
    pk.us[0] = f2bf(v.x); pk.us[1] = f2bf(v.y); pk.us[2] = f2bf(v.z); pk.us[3] = f2bf(v.w);
    *(u64_t*)&xb[i * 4] = pk.u;
  } else if (b < PB_CVTW + PB_TAB + PB_CVTX + PB_PART) {
    int pb = b - PB_CVTW - PB_TAB - PB_CVTX;
    if (tid < 8) lcnt[tid] = 0;
    int z = pb * 49 + tid;
    if (tid < 49 && z < NN) bcnt[z] = 0;
    __syncthreads();
    int e0 = pb * EPB;
    int e1 = min(e0 + EPB, EE);
    for (int e = e0 + tid; e < e1; e += 256) {
      int d = __builtin_nontemporal_load(dst + e);
      int s = __builtin_nontemporal_load(src + e);
      float di = __builtin_nontemporal_load(dist + e);
      float u = di * (float)(TT - 1);
      int t0 = (int)(fminf(fmaxf(u, 0.f), (float)(TT - 1)) + 0.5f);
      if (t0 > TT - 1) t0 = TT - 1;
      int r = d / SRW;
      int pos = atomicAdd(&lcnt[r], 1);
      if (pos < SEGC) {
        uint_t* sp = seg + (((size_t)(r << 10) + pb) * SEGC + pos) * 2;
        sp[0] = (uint_t)d;
        sp[1] = ((uint_t)s << 9) | (uint_t)(t0 + 1);
      }
    }
    __syncthreads();
    if (tid < 8) segcnt[(tid << 10) + pb] = min(lcnt[tid], SEGC);
  } else {
    for (int i = tid; i < GG * HH; i += 256) gsum[i] = 0.f;
    // zero sentinel row (row 0) of each layer's filter table
    for (int i = tid; i < LL * HH; i += 256)
      tables[(size_t)(i >> 7) * TTP * HH + (i & 127)] = 0;
    if (tid < GG) {
      int g = tid;
      int lo = 0, hi = NN;
      while (lo < hi) { int m = (lo + hi) >> 1; if (gid[m] < g) lo = m + 1; else hi = m; }
      int b0 = lo;
      lo = 0; hi = NN;
      int g1 = g + 1;
      while (lo < hi) { int m = (lo + hi) >> 1; if (gid[m] < g1) lo = m + 1; else hi = m; }
      gcnt[g] = lo - b0;
    }
  }
}

// ---------------- combined: per-region scatter (blocks 0..SCB) | gemm1 (rest) ----------------
__global__ __launch_bounds__(256) void scatter_gemm1(
    const uint_t* __restrict__ seg, const int* __restrict__ segcnt,
    int* __restrict__ bcnt, uint_t* __restrict__ epad,
    const ushort_t* __restrict__ xb, const ushort_t* __restrict__ wt,
    const float* __restrict__ b1_0, ushort_t* __restrict__ pbuf) {
  int tid = threadIdx.x;
  if (blockIdx.x < SCB) {
    int r = blockIdx.x & 7;
    int sub = blockIdx.x >> 3;
    for (int b = sub; b < ABLK; b += SUBB) {
      int cnt = segcnt[(r << 10) + b];
      const uint_t* sp = seg + ((size_t)(r << 10) + b) * SEGC * 2;
      for (int i = tid; i < cnt; i += 256) {
        uint_t ex = __builtin_nontemporal_load(sp + i * 2);
        uint_t ey = __builtin_nontemporal_load(sp + i * 2 + 1);
        int slot = atomicAdd(&bcnt[ex], 1);
        if (slot < BD) epad[(size_t)ex * BD + slot] = ey;
      }
    }
  } else {
    int tile = blockIdx.x - SCB;
    int lane = tid & 63, wave = tid >> 6, m = lane & 15, quad = lane >> 4;
    int rowbase = tile * 16, colbase = wave * 32;
    const ushort_t* arow = xb + (size_t)(rowbase + m) * FF;
    const ushort_t* brow0 = wt + (size_t)(colbase + m) * FF;
    const ushort_t* brow1 = wt + (size_t)(colbase + 16 + m) * FF;
    f32x4 acc0 = {0.f, 0.f, 0.f, 0.f};
    f32x4 acc1 = {0.f, 0.f, 0.f, 0.f};
    for (int kc = 0; kc < FF; kc += 32) {
      int k = kc + quad * 8;
      union { uint4 u; s8v v; } a, b0, b1;
      a.u  = *(const uint4*)(arow + k);
      b0.u = *(const uint4*)(brow0 + k);
      b1.u = *(const uint4*)(brow1 + k);
      acc0 = __builtin_amdgcn_mfma_f32_16x16x32_bf16(a.v, b0.v, acc0, 0, 0, 0);
      acc1 = __builtin_amdgcn_mfma_f32_16x16x32_bf16(a.v, b1.v, acc1, 0, 0, 0);
    }
    float bb0 = b1_0[colbase + m];
    float bb1 = b1_0[colbase + 16 + m];
#pragma unroll
    for (int reg = 0; reg < 4; ++reg) {
      int row = rowbase + quad * 4 + reg;
      pbuf[(size_t)row * HH + colbase + m] = f2h(acc0[reg] + bb0);
      pbuf[(size_t)row * HH + colbase + 16 + m] = f2h(acc1[reg] + bb1);
    }
  }
}

// ---------------- fused layer: f16 edge_agg + LDS table + gemm2/gemm1 ----------------
// Table (TTP x 128 f16 = 64.2 KB) staged in LDS (bank-swizzled) -> table reads
// leave the TA pipe. pIn gather is edge-PAIRED: lanes 0-31 edge A, 32-63 edge B,
// dwordx2/lane -> ONE wave-load covers two 256-B rows. TA instr/edge: 2 -> 0.5.
// Cross-half combine via 4x shfl_xor(32) per node at the end.
__global__ __launch_bounds__(512) void fused_layer(
    const ushort_t* __restrict__ pIn, const ushort_t* __restrict__ tabG,
    const uint_t* __restrict__ epad, const int* __restrict__ bcnt,
    const ushort_t* __restrict__ WT2, const float* __restrict__ b2l,
    const ushort_t* __restrict__ WT1, const float* __restrict__ b1l,
    ushort_t* __restrict__ OUT, int last) {
  __shared__ ushort_t Tab[TTP * HH];  // 65792 B
  __shared__ ushort_t At[16 * 128];
  __shared__ ushort_t T[16 * 128];
  int tid = threadIdx.x;
  int lane = tid & 63;
  int wv = tid >> 6;  // 0..7
  int tile = blockIdx.x;
  int l32 = lane & 31;

  // stage table into LDS with per-row XOR swizzle (8B units) for bank spread
  {
    const u64_t* g = (const u64_t*)tabG;
    u64_t* s = (u64_t*)Tab;
    for (int i = tid; i < (TTP * HH) / 4; i += 512) {
      int row = i >> 5, j = i & 31;
      s[(row << 5) + (j ^ (row & 31))] = g[i];
    }
  }

  int baseV = tile * 16 + wv * 2;
  uint_t ed[2];
  float a0[2], a1[2], a2[2], a3[2];
  int B = 0;
#pragma unroll
  for (int i = 0; i < 2; ++i) {
    int n = min(bcnt[baseV + i], BD);
    ed[i] = (lane < n) ? epad[(size_t)(baseV + i) * BD + lane] : 0u;
    B = max(B, (n + 1) >> 1);
    a0[i] = 0.f; a1[i] = 0.f; a2[i] = 0.f; a3[i] = 0.f;
  }
  __syncthreads();

  const u64_t* pu = (const u64_t*)pIn;   // row stride 32 u64
  const u64_t* tu = (const u64_t*)Tab;
  bool hi = lane >= 32;
  for (int c = 0; c < B; ++c) {
#pragma unroll
    for (int i = 0; i < 2; ++i) {
      uint_t eA = (uint_t)__builtin_amdgcn_readlane((int)ed[i], 2 * c);
      uint_t eB = (uint_t)__builtin_amdgcn_readlane((int)ed[i], 2 * c + 1);
      uint_t e = hi ? eB : eA;
      union { u64_t u; uint_t w[2]; } pv, fv;
      pv.u = pu[(size_t)(e >> 9) * 32 + l32];
      uint_t trow = e & 511u;
      fv.u = tu[(trow << 5) + (l32 ^ (trow & 31u))];
      a0[i] += h_lo(pv.w[0]) * h_lo(fv.w[0]);
      a1[i] += h_hi(pv.w[0]) * h_hi(fv.w[0]);
      a2[i] += h_lo(pv.w[1]) * h_lo(fv.w[1]);
      a3[i] += h_hi(pv.w[1]) * h_hi(fv.w[1]);
    }
  }
#pragma unroll
  for (int i = 0; i < 2; ++i) {
    a0[i] += __shfl_xor(a0[i], 32);
    a1[i] += __shfl_xor(a1[i], 32);
    a2[i] += __shfl_xor(a2[i], 32);
    a3[i] += __shfl_xor(a3[i], 32);
  }
  if (lane < 32) {
#pragma unroll
    for (int i = 0; i < 2; ++i) {
      int r = wv * 2 + i;
      int d0 = l32 * 2, d1 = d0 + 1;
      ((uint_t*)At)[r * 64 + (((d0 >> 2) ^ r) << 2) + (d0 & 3)] =
          (uint_t)f2bf(a0[i]) | ((uint_t)f2bf(a1[i]) << 16);
      ((uint_t*)At)[r * 64 + (((d1 >> 2) ^ r) << 2) + (d1 & 3)] =
          (uint_t)f2bf(a2[i]) | ((uint_t)f2bf(a3[i]) << 16);
    }
  }
  __syncthreads();
  int m = lane & 15, quad = lane >> 4;
  int rowbase = tile * 16, colbase = wv * 16;
  {
    const ushort_t* brow0 = WT2 + (size_t)(colbase + m) * HH;
    f32x4 acc0 = {0.f, 0.f, 0.f, 0.f};
    for (int kc = 0; kc < HH; kc += 32) {
      int k = kc + quad * 8;
      int g = k >> 3;
      union { uint4 u; s8v v; } a, b0;
      a.u = *(const uint4*)&At[m * 128 + ((g ^ m) << 3)];
      b0.u = *(const uint4*)(brow0 + k);
      acc0 = __builtin_amdgcn_mfma_f32_16x16x32_bf16(a.v, b0.v, acc0, 0, 0, 0);
    }
    float bb0 = b2l[colbase + m];
    if (last) {
#pragma unroll
      for (int reg = 0; reg < 4; ++reg) {
        int row = rowbase + quad * 4 + reg;
        OUT[(size_t)row * HH + colbase + m] = f2bf(fmaxf(acc0[reg] + bb0, 0.f));
      }
      return;
    }
#pragma unroll
    for (int reg = 0; reg < 4; ++reg) {
      int r = quad * 4 + reg;
      float v0 = fmaxf(acc0[reg] + bb0, 0.f);
      int c0 = colbase + m;
      T[r * 128 + (((c0 >> 3) ^ r) << 3) + (c0 & 7)] = f2bf(v0);
    }
  }
  __syncthreads();
  {
    const ushort_t* brow0 = WT1 + (size_t)(colbase + m) * HH;
    f32x4 acc0 = {0.f, 0.f, 0.f, 0.f};
    for (int kc = 0; kc < HH; kc += 32) {
      int k0 = kc + quad * 8;
      int g = k0 >> 3;
      union { uint4 u; s8v v; } a, b0;
      a.u = *(const uint4*)&T[m * 128 + ((g ^ m) << 3)];
      b0.u = *(const uint4*)(brow0 + k0);
      acc0 = __builtin_amdgcn_mfma_f32_16x16x32_bf16(a.v, b0.v, acc0, 0, 0, 0);
    }
    float bb0 = b1l[colbase + m];
#pragma unroll
    for (int reg = 0; reg < 4; ++reg) {
      int row = rowbase + quad * 4 + reg;
      OUT[(size_t)row * HH + colbase + m] = f2h(acc0[reg] + bb0);
    }
  }
}

// ---------------- pool: strip-parallel run-accumulate ----------------
__global__ __launch_bounds__(128) void pool_kernel(const ushort_t* __restrict__ h, const int* __restrict__ gid,
                                                   float* __restrict__ gsum) {
  int j = threadIdx.x;
  int i0 = blockIdx.x * 128;
  int i1 = min(i0 + 128, NN);
  if (i0 >= NN) return;
  float acc = 0.f;
  int gcur = gid[i0];
  for (int i = i0; i < i1; ++i) {
    int g = gid[i];
    if (g != gcur) {
      atomicAdd(&gsum[gcur * HH + j], acc);
      acc = 0.f;
      gcur = g;
    }
    acc += bf1f(h[(size_t)i * HH + j]);
  }
  atomicAdd(&gsum[gcur * HH + j], acc);
}

__global__ __launch_bounds__(128) void final_kernel(const float* __restrict__ gsum, const int* __restrict__ gcnt,
                                                    const float* __restrict__ fc_w, const float* __restrict__ fc_b,
                                                    float* __restrict__ out) {
  int g = blockIdx.x, j = threadIdx.x;
  __shared__ float pooled[HH];
  __shared__ float logits[CC];
  __shared__ float lse;
  float cnt = fmaxf((float)gcnt[g], 1.0f);
  pooled[j] = gsum[g * HH + j] / cnt;
  __syncthreads();
  if (j < CC) {
    float s = fc_b[j];
    for (int k = 0; k < HH; ++k) s += pooled[k] * fc_w[k * CC + j];
    logits[j] = s;
  }
  __syncthreads();
  if (j == 0) {
    float m = -1e30f;
    for (int c = 0; c < CC; ++c) m = fmaxf(m, logits[c]);
    float s = 0.f;
    for (int c = 0; c < CC; ++c) s += expf(logits[c] - m);
    lse = m + logf(s);
  }
  __syncthreads();
  if (j < CC) out[g * CC + j] = logits[j] - lse;
}

extern "C" void kernel_launch(void* const* d_in, const int* in_sizes, int n_in,
                              void* d_out, int out_size, void* d_ws, size_t ws_size,
                              hipStream_t stream) {
  const float* x       = (const float*)d_in[0];
  const float* edist   = (const float*)d_in[1];
  const int*   esrc    = (const int*)d_in[2];
  const int*   edst    = (const int*)d_in[3];
  const int*   gid     = (const int*)d_in[4];
  const float* W1_0    = (const float*)d_in[5];
  const float* b1_0    = (const float*)d_in[6];
  const float* W1_rest = (const float*)d_in[7];
  const float* b1_rest = (const float*)d_in[8];
  const float* Wf1     = (const float*)d_in[9];
  const float* bf1     = (const float*)d_in[10];
  const float* Wf2     = (const float*)d_in[11];
  const float* bf2     = (const float*)d_in[12];
  const float* W2      = (const float*)d_in[13];
  const float* b2      = (const float*)d_in[14];
  const float* fc_w    = (const float*)d_in[15];
  const float* fc_b    = (const float*)d_in[16];
  float* out = (float*)d_out;

  char* ws = (char*)d_ws;
  size_t o = 0;
  auto alloc = [&](size_t bytes) {
    void* p = ws + o;
    o += (bytes + 255) & ~(size_t)255;
    return p;
  };
  ushort_t* tables = (ushort_t*)alloc(sizeof(ushort_t) * (size_t)LL * TTP * HH);
  ushort_t* xb     = (ushort_t*)alloc(sizeof(ushort_t) * (size_t)NN * FF);
  ushort_t* wt     = (ushort_t*)alloc(sizeof(ushort_t) * 8 * HH * HH);
  ushort_t* pbuf   = (ushort_t*)alloc(sizeof(ushort_t) * (size_t)NN * HH);
  ushort_t* pbuf2  = (ushort_t*)alloc(sizeof(ushort_t) * (size_t)NN * HH);
  ushort_t* hbuf   = (ushort_t*)alloc(sizeof(ushort_t) * (size_t)NN * HH);
  int*      bcnt   = (int*)alloc(sizeof(int) * NN);
  uint_t*   epad   = (uint_t*)alloc(sizeof(uint_t) * (size_t)NN * BD);
  uint_t*   seg    = (uint_t*)alloc(sizeof(uint_t) * (size_t)2 * 8 * ABLK * SEGC);
  int*      segcnt = (int*)alloc(sizeof(int) * 8 * ABLK);
  float*    gsum   = (float*)alloc(sizeof(float) * GG * HH);
  int*      gcnt   = (int*)alloc(sizeof(int) * GG);

  const int prepBlocks = PB_CVTW + PB_TAB + PB_CVTX + PB_PART + 1;  // 4222
  prep<<<prepBlocks, 256, 0, stream>>>(x, xb, W1_0, W1_rest, W2, wt,
                                       Wf1, bf1, Wf2, bf2, tables,
                                       edst, esrc, edist, seg, segcnt, bcnt,
                                       gid, gcnt, gsum);
  scatter_gemm1<<<SCB + GEMMB, 256, 0, stream>>>(seg, segcnt, bcnt, epad,
                                                 xb, wt, b1_0, pbuf);

  ushort_t* pIn = pbuf;
  ushort_t* pOut = pbuf2;
  for (int l = 0; l < LL; ++l) {
    int last = (l == LL - 1);
    fused_layer<<<GEMMB, 512, 0, stream>>>(
        pIn, tables + (size_t)l * TTP * HH, epad, bcnt,
        wt + (size_t)(4 + l) * HH * HH, b2 + (size_t)l * HH,
        last ? nullptr : (wt + (size_t)(1 + l) * HH * HH),
        last ? nullptr : (b1_rest + (size_t)l * HH),
        last ? hbuf : pOut, last);
    ushort_t* tmp = pIn; pIn = pOut; pOut = tmp;
  }

  pool_kernel<<<(NN + 127) / 128, 128, 0, stream>>>(hbuf, gid, gsum);
  final_kernel<<<GG, 128, 0, stream>>>(gsum, gcnt, fc_w, fc_b, out);
}

// Round 8
// 436.893 us; speedup vs baseline: 1.2651x; 1.2651x over previous
//
#include <hip/hip_runtime.h>
#include <math.h>

#define NN 50000
#define EE 800000
#define FF 64
#define HH 128
#define LL 4
#define GG 64
#define CC 10
#define TT 256     // table points per layer (8-bit index; TT=256 accuracy-proven R6)
#define TTP 257    // +1 zero row at index 0 (sentinel); real rows 1..256
#define BD 64      // padded bucket capacity per dst
#define ABLK 1024  // phase-A part blocks
#define EPB 782    // edges per phase-A block
#define SEGC 192   // per (block,region) segment capacity
#define SUBB 96    // phase-B sub-blocks per region
#define SRW 6250   // dst region width (NN/8)

// prep kernel block ranges
#define PB_CVTW 8
#define PB_TAB ((TT / 16) * LL)      // 64
#define PB_CVTX (NN * FF / 4 / 256)  // 3125
#define PB_PART ABLK

#define SCB (8 * SUBB)   // 768 scatter blocks in the combined dispatch
#define GEMMB (NN / 16)  // 3125 gemm tiles

typedef unsigned short ushort_t;
typedef unsigned int uint_t;
typedef unsigned long long u64_t;

typedef short s8v __attribute__((ext_vector_type(8)));
typedef float f32x4 __attribute__((ext_vector_type(4)));

__device__ inline ushort_t f2bf(float f) {
  uint_t u = __float_as_uint(f);
  uint_t r = (u + 0x7FFFu + ((u >> 16) & 1u)) >> 16;
  return (ushort_t)r;
}
__device__ inline float bf1f(ushort_t v) { return __uint_as_float(((uint_t)v) << 16); }
__device__ inline ushort_t f2h(float f) {
  union { _Float16 h[2]; ushort_t us[2]; } c;
  c.h[0] = (_Float16)f;
  return c.us[0];
}

// ---------------- fused prep: cvt_w | build int8 tables | cvt_x | part_edges | gcnt+gsum ----------------
__global__ __launch_bounds__(256) void prep(
    const float* __restrict__ x, ushort_t* __restrict__ xb,
    const float* __restrict__ W1_0, const float* __restrict__ W1_rest,
    const float* __restrict__ W2, ushort_t* __restrict__ wt,
    const float* __restrict__ Wf1, const float* __restrict__ bf1,
    const float* __restrict__ Wf2, const float* __restrict__ bf2,
    char* __restrict__ tabQ, float* __restrict__ tabS,
    const int* __restrict__ dst, const int* __restrict__ src,
    const float* __restrict__ dist,
    uint_t* __restrict__ seg, int* __restrict__ segcnt, int* __restrict__ bcnt,
    const int* __restrict__ gid, int* __restrict__ gcnt, float* __restrict__ gsum) {
  __shared__ float rbf[16][HH];
  __shared__ float hid[16][HH];
  __shared__ int lcnt[8];
  __shared__ uint_t rmx[16];
  int tid = threadIdx.x;
  int b = blockIdx.x;

  if (b < PB_CVTW) {
    int mid = b;
    const float* srcm; int K;
    if (mid == 0) { srcm = W1_0; K = FF; }
    else if (mid < 4) { srcm = W1_rest + (size_t)(mid - 1) * HH * HH; K = HH; }
    else { srcm = W2 + (size_t)(mid - 4) * HH * HH; K = HH; }
    ushort_t* dstm = wt + (size_t)mid * HH * HH;
    for (int idx = tid; idx < K * HH; idx += 256) {
      int k = idx >> 7, n = idx & 127;
      dstm[n * K + k] = f2bf(srcm[idx]);
    }
  } else if (b < PB_CVTW + PB_TAB) {
    int bb = b - PB_CVTW;
    int l = bb & 3;
    int tb = (bb >> 2) * 16;
    int j = tid & 127;
    if (tid < 16) rmx[tid] = 0u;
    float c = j * (1.0f / (HH - 1));
#pragma unroll
    for (int tt2 = 0; tt2 < 16; ++tt2) {
      float d = (tb + tt2) * (1.0f / (TT - 1));
      float dd = d - c;
      rbf[tt2][j] = expf(-10.0f * dd * dd);
    }
    __syncthreads();
    const float* W1f = Wf1 + (size_t)l * HH * HH;
    float s[16];
    float bb1 = bf1[l * HH + j];
#pragma unroll
    for (int tt2 = 0; tt2 < 16; ++tt2) s[tt2] = bb1;
    for (int k = 0; k < HH; ++k) {
      float wk = W1f[(size_t)k * HH + j];
#pragma unroll
      for (int tt2 = 0; tt2 < 16; ++tt2) s[tt2] += rbf[tt2][k] * wk;
    }
#pragma unroll
    for (int tt2 = 0; tt2 < 16; ++tt2)
      hid[tt2][j] = fmaxf(s[tt2], 0.f) + log1pf(expf(-fabsf(s[tt2]))) - 0.6931472f;
    __syncthreads();
    const float* W2f = Wf2 + (size_t)l * HH * HH;
    float bb2 = bf2[l * HH + j];
#pragma unroll
    for (int tt2 = 0; tt2 < 16; ++tt2) s[tt2] = bb2;
    for (int k = 0; k < HH; ++k) {
      float wk = W2f[(size_t)k * HH + j];
#pragma unroll
      for (int tt2 = 0; tt2 < 16; ++tt2) s[tt2] += hid[tt2][k] * wk;
    }
    if (tid < 128) {
#pragma unroll
      for (int tt2 = 0; tt2 < 16; ++tt2)
        atomicMax(&rmx[tt2], __float_as_uint(fabsf(s[tt2])));
    }
    __syncthreads();
    if (tid < 128) {
      // rows shifted by +1: row 0 of each layer's table is the zero sentinel row
#pragma unroll
      for (int tt2 = 0; tt2 < 16; ++tt2) {
        float inv = 127.0f / fmaxf(__uint_as_float(rmx[tt2]), 1e-30f);
        tabQ[((size_t)l * TTP + 1 + tb + tt2) * HH + j] = (char)(int)rintf(s[tt2] * inv);
      }
    }
    if (tid < 16)
      tabS[(size_t)l * TTP + 1 + tb + tid] = __uint_as_float(rmx[tid]) * (1.0f / 127.0f);
  } else if (b < PB_CVTW + PB_TAB + PB_CVTX) {
    int i = (b - PB_CVTW - PB_TAB) * 256 + tid;
    const float4* x4 = (const float4*)x;
    float4 v = x4[i];
    union { ushort_t us[4]; u64_t u; } pk;
    pk.us[0] = f2bf(v.x); pk.us[1] = f2bf(v.y); pk.us[2] = f2bf(v.z); pk.us[3] = f2bf(v.w);
    *(u64_t*)&xb[i * 4] = pk.u;
  } else if (b < PB_CVTW + PB_TAB + PB_CVTX + PB_PART) {
    int pb = b - PB_CVTW - PB_TAB - PB_CVTX;
    if (tid < 8) lcnt[tid] = 0;
    int z = pb * 49 + tid;
    if (tid < 49 && z < NN) bcnt[z] = 0;
    __syncthreads();
    int e0 = pb * EPB;
    int e1 = min(e0 + EPB, EE);
    for (int e = e0 + tid; e < e1; e += 256) {
      int d = __builtin_nontemporal_load(dst + e);
      int s = __builtin_nontemporal_load(src + e);
      float di = __builtin_nontemporal_load(dist + e);
      float u = di * (float)(TT - 1);
      int t0 = (int)(fminf(fmaxf(u, 0.f), (float)(TT - 1)) + 0.5f);
      if (t0 > TT - 1) t0 = TT - 1;
      int r = d / SRW;
      int pos = atomicAdd(&lcnt[r], 1);
      if (pos < SEGC) {
        uint_t* sp = seg + (((size_t)(r << 10) + pb) * SEGC + pos) * 2;
        sp[0] = (uint_t)d;
        sp[1] = ((uint_t)s << 9) | (uint_t)(t0 + 1);
      }
    }
    __syncthreads();
    if (tid < 8) segcnt[(tid << 10) + pb] = min(lcnt[tid], SEGC);
  } else {
    for (int i = tid; i < GG * HH; i += 256) gsum[i] = 0.f;
    // zero sentinel row (row 0) of each layer's table; scale 0 too
    for (int i = tid; i < LL * HH; i += 256)
      tabQ[(size_t)(i >> 7) * TTP * HH + (i & 127)] = 0;
    if (tid < LL) tabS[(size_t)tid * TTP] = 0.f;
    if (tid >= 32 && tid < 32 + GG) {
      int g = tid - 32;
      int lo = 0, hi = NN;
      while (lo < hi) { int m = (lo + hi) >> 1; if (gid[m] < g) lo = m + 1; else hi = m; }
      int b0 = lo;
      lo = 0; hi = NN;
      int g1 = g + 1;
      while (lo < hi) { int m = (lo + hi) >> 1; if (gid[m] < g1) lo = m + 1; else hi = m; }
      gcnt[g] = lo - b0;
    }
  }
}

// ---------------- combined: per-region scatter (blocks 0..SCB) | gemm1 (rest) ----------------
// gemm1 epilogue quantizes its output rows to int8 + per-row scale (layer-0 gather input).
__global__ __launch_bounds__(256) void scatter_gemm1(
    const uint_t* __restrict__ seg, const int* __restrict__ segcnt,
    int* __restrict__ bcnt, uint_t* __restrict__ epad,
    const ushort_t* __restrict__ xb, const ushort_t* __restrict__ wt,
    const float* __restrict__ b1_0, char* __restrict__ q8Out,
    float* __restrict__ sclOut) {
  __shared__ uint_t rmaxL[16];
  int tid = threadIdx.x;
  if (blockIdx.x < SCB) {
    int r = blockIdx.x & 7;
    int sub = blockIdx.x >> 3;
    for (int b = sub; b < ABLK; b += SUBB) {
      int cnt = segcnt[(r << 10) + b];
      const uint_t* sp = seg + ((size_t)(r << 10) + b) * SEGC * 2;
      for (int i = tid; i < cnt; i += 256) {
        uint_t ex = __builtin_nontemporal_load(sp + i * 2);
        uint_t ey = __builtin_nontemporal_load(sp + i * 2 + 1);
        int slot = atomicAdd(&bcnt[ex], 1);
        if (slot < BD) epad[(size_t)ex * BD + slot] = ey;
      }
    }
  } else {
    if (tid < 16) rmaxL[tid] = 0u;
    int tile = blockIdx.x - SCB;
    int lane = tid & 63, wave = tid >> 6, m = lane & 15, quad = lane >> 4;
    int rowbase = tile * 16, colbase = wave * 32;
    const ushort_t* arow = xb + (size_t)(rowbase + m) * FF;
    const ushort_t* brow0 = wt + (size_t)(colbase + m) * FF;
    const ushort_t* brow1 = wt + (size_t)(colbase + 16 + m) * FF;
    f32x4 acc0 = {0.f, 0.f, 0.f, 0.f};
    f32x4 acc1 = {0.f, 0.f, 0.f, 0.f};
    for (int kc = 0; kc < FF; kc += 32) {
      int k = kc + quad * 8;
      union { uint4 u; s8v v; } a, b0, b1;
      a.u  = *(const uint4*)(arow + k);
      b0.u = *(const uint4*)(brow0 + k);
      b1.u = *(const uint4*)(brow1 + k);
      acc0 = __builtin_amdgcn_mfma_f32_16x16x32_bf16(a.v, b0.v, acc0, 0, 0, 0);
      acc1 = __builtin_amdgcn_mfma_f32_16x16x32_bf16(a.v, b1.v, acc1, 0, 0, 0);
    }
    float bb0 = b1_0[colbase + m];
    float bb1 = b1_0[colbase + 16 + m];
    float v0r[4], v1r[4];
#pragma unroll
    for (int reg = 0; reg < 4; ++reg) {
      v0r[reg] = acc0[reg] + bb0;
      v1r[reg] = acc1[reg] + bb1;
      int r = quad * 4 + reg;
      atomicMax(&rmaxL[r], __float_as_uint(fmaxf(fabsf(v0r[reg]), fabsf(v1r[reg]))));
    }
    __syncthreads();
#pragma unroll
    for (int reg = 0; reg < 4; ++reg) {
      int r = quad * 4 + reg;
      int row = rowbase + r;
      float inv = 127.0f / fmaxf(__uint_as_float(rmaxL[r]), 1e-30f);
      q8Out[(size_t)row * HH + colbase + m] = (char)(int)rintf(v0r[reg] * inv);
      q8Out[(size_t)row * HH + colbase + 16 + m] = (char)(int)rintf(v1r[reg] * inv);
    }
    if (tid < 16) sclOut[rowbase + tid] = __uint_as_float(rmaxL[tid]) * (1.0f / 127.0f);
  }
}

// ---------------- fused layer: int8 edge_agg + int8 L1-resident table + gemm2/gemm1 ----------------
// R3 structure (512 thr, 2 nodes/wave, batch-4 loads, no lane-split). Per edge:
// pIn int8 row = 128 B = 1 L2-line (vs bf16's 2); table int8 TT=256 = 33 KB ->
// L1-resident ~0 lines. Scales via UNIFORM s_load (edge word from readlane is
// SGPR) -> scalar K$ path, off the vector MSHR budget. Sentinel edge 0 ->
// table row 0 zero + scale 0 -> contributes exactly 0.
__global__ __launch_bounds__(512) void fused_layer(
    const char* __restrict__ q8In, const float* __restrict__ sclIn,
    const char* __restrict__ tabQ, const float* __restrict__ tabS,
    const uint_t* __restrict__ epad, const int* __restrict__ bcnt,
    const ushort_t* __restrict__ WT2, const float* __restrict__ b2l,
    const ushort_t* __restrict__ WT1, const float* __restrict__ b1l,
    char* __restrict__ q8Out, float* __restrict__ sclOut,
    ushort_t* __restrict__ hbuf, int last) {
  __shared__ ushort_t At[16 * 128];
  __shared__ ushort_t T[16 * 128];
  __shared__ uint_t rmaxL[16];
  int tid = threadIdx.x;
  int lane = tid & 63;
  int wv = tid >> 6;  // 0..7
  int tile = blockIdx.x;
  if (tid < 16) rmaxL[tid] = 0u;

  const ushort_t* pq = (const ushort_t*)q8In;  // row stride 64 ushorts (128 B)
  const ushort_t* tq = (const ushort_t*)tabQ;

  int baseV = tile * 16 + wv * 2;
  uint_t ed[2];
  float ax[2], ay[2];
  int B = 0;
#pragma unroll
  for (int i = 0; i < 2; ++i) {
    int n = min(bcnt[baseV + i], BD);
    ed[i] = (lane < n) ? epad[(size_t)(baseV + i) * BD + lane] : 0u;
    B = max(B, (n + 3) >> 2);
    ax[i] = 0.f; ay[i] = 0.f;
  }
  for (int c = 0; c < B; ++c) {
    uint_t pv[2][4], fv[2][4];
    float sc[2][4];
#pragma unroll
    for (int i = 0; i < 2; ++i) {
#pragma unroll
      for (int k = 0; k < 4; ++k) {
        uint_t e = (uint_t)__builtin_amdgcn_readlane((int)ed[i], c * 4 + k);
        pv[i][k] = pq[(size_t)(e >> 9) * 64 + lane];
        fv[i][k] = tq[(size_t)(e & 511u) * 64 + lane];
        sc[i][k] = sclIn[e >> 9] * tabS[e & 511u];
      }
    }
#pragma unroll
    for (int i = 0; i < 2; ++i) {
#pragma unroll
      for (int k = 0; k < 4; ++k) {
        int wp = (int)pv[i][k], wf = (int)fv[i][k];
        float p0 = (float)((wp << 24) >> 24);
        float p1 = (float)((wp << 16) >> 24);
        float f0 = (float)((wf << 24) >> 24);
        float f1 = (float)((wf << 16) >> 24);
        ax[i] += (p0 * f0) * sc[i][k];
        ay[i] += (p1 * f1) * sc[i][k];
      }
    }
  }
#pragma unroll
  for (int i = 0; i < 2; ++i) {
    int r = wv * 2 + i;
    uint_t packed = (uint_t)f2bf(ax[i]) | ((uint_t)f2bf(ay[i]) << 16);
    ((uint_t*)At)[r * 64 + (((lane >> 2) ^ r) << 2) + (lane & 3)] = packed;
  }
  __syncthreads();
  int m = lane & 15, quad = lane >> 4;
  int rowbase = tile * 16, colbase = wv * 16;
  {
    const ushort_t* brow0 = WT2 + (size_t)(colbase + m) * HH;
    f32x4 acc0 = {0.f, 0.f, 0.f, 0.f};
    for (int kc = 0; kc < HH; kc += 32) {
      int k = kc + quad * 8;
      int g = k >> 3;
      union { uint4 u; s8v v; } a, b0;
      a.u = *(const uint4*)&At[m * 128 + ((g ^ m) << 3)];
      b0.u = *(const uint4*)(brow0 + k);
      acc0 = __builtin_amdgcn_mfma_f32_16x16x32_bf16(a.v, b0.v, acc0, 0, 0, 0);
    }
    float bb0 = b2l[colbase + m];
    if (last) {
#pragma unroll
      for (int reg = 0; reg < 4; ++reg) {
        int row = rowbase + quad * 4 + reg;
        hbuf[(size_t)row * HH + colbase + m] = f2bf(fmaxf(acc0[reg] + bb0, 0.f));
      }
      return;
    }
#pragma unroll
    for (int reg = 0; reg < 4; ++reg) {
      int r = quad * 4 + reg;
      float v0 = fmaxf(acc0[reg] + bb0, 0.f);
      int c0 = colbase + m;
      T[r * 128 + (((c0 >> 3) ^ r) << 3) + (c0 & 7)] = f2bf(v0);
    }
  }
  __syncthreads();
  {
    const ushort_t* brow0 = WT1 + (size_t)(colbase + m) * HH;
    f32x4 acc0 = {0.f, 0.f, 0.f, 0.f};
    for (int kc = 0; kc < HH; kc += 32) {
      int k0 = kc + quad * 8;
      int g = k0 >> 3;
      union { uint4 u; s8v v; } a, b0;
      a.u = *(const uint4*)&T[m * 128 + ((g ^ m) << 3)];
      b0.u = *(const uint4*)(brow0 + k0);
      acc0 = __builtin_amdgcn_mfma_f32_16x16x32_bf16(a.v, b0.v, acc0, 0, 0, 0);
    }
    float bb0 = b1l[colbase + m];
    float v0r[4];
#pragma unroll
    for (int reg = 0; reg < 4; ++reg) {
      v0r[reg] = acc0[reg] + bb0;
      int r = quad * 4 + reg;
      atomicMax(&rmaxL[r], __float_as_uint(fabsf(v0r[reg])));
    }
    __syncthreads();
#pragma unroll
    for (int reg = 0; reg < 4; ++reg) {
      int r = quad * 4 + reg;
      int row = rowbase + r;
      float inv = 127.0f / fmaxf(__uint_as_float(rmaxL[r]), 1e-30f);
      q8Out[(size_t)row * HH + colbase + m] = (char)(int)rintf(v0r[reg] * inv);
    }
    if (tid < 16) sclOut[rowbase + tid] = __uint_as_float(rmaxL[tid]) * (1.0f / 127.0f);
  }
}

// ---------------- pool: strip-parallel run-accumulate ----------------
__global__ __launch_bounds__(128) void pool_kernel(const ushort_t* __restrict__ h, const int* __restrict__ gid,
                                                   float* __restrict__ gsum) {
  int j = threadIdx.x;
  int i0 = blockIdx.x * 128;
  int i1 = min(i0 + 128, NN);
  if (i0 >= NN) return;
  float acc = 0.f;
  int gcur = gid[i0];
  for (int i = i0; i < i1; ++i) {
    int g = gid[i];
    if (g != gcur) {
      atomicAdd(&gsum[gcur * HH + j], acc);
      acc = 0.f;
      gcur = g;
    }
    acc += bf1f(h[(size_t)i * HH + j]);
  }
  atomicAdd(&gsum[gcur * HH + j], acc);
}

__global__ __launch_bounds__(128) void final_kernel(const float* __restrict__ gsum, const int* __restrict__ gcnt,
                                                    const float* __restrict__ fc_w, const float* __restrict__ fc_b,
                                                    float* __restrict__ out) {
  int g = blockIdx.x, j = threadIdx.x;
  __shared__ float pooled[HH];
  __shared__ float logits[CC];
  __shared__ float lse;
  float cnt = fmaxf((float)gcnt[g], 1.0f);
  pooled[j] = gsum[g * HH + j] / cnt;
  __syncthreads();
  if (j < CC) {
    float s = fc_b[j];
    for (int k = 0; k < HH; ++k) s += pooled[k] * fc_w[k * CC + j];
    logits[j] = s;
  }
  __syncthreads();
  if (j == 0) {
    float m = -1e30f;
    for (int c = 0; c < CC; ++c) m = fmaxf(m, logits[c]);
    float s = 0.f;
    for (int c = 0; c < CC; ++c) s += expf(logits[c] - m);
    lse = m + logf(s);
  }
  __syncthreads();
  if (j < CC) out[g * CC + j] = logits[j] - lse;
}

extern "C" void kernel_launch(void* const* d_in, const int* in_sizes, int n_in,
                              void* d_out, int out_size, void* d_ws, size_t ws_size,
                              hipStream_t stream) {
  const float* x       = (const float*)d_in[0];
  const float* edist   = (const float*)d_in[1];
  const int*   esrc    = (const int*)d_in[2];
  const int*   edst    = (const int*)d_in[3];
  const int*   gid     = (const int*)d_in[4];
  const float* W1_0    = (const float*)d_in[5];
  const float* b1_0    = (const float*)d_in[6];
  const float* W1_rest = (const float*)d_in[7];
  const float* b1_rest = (const float*)d_in[8];
  const float* Wf1     = (const float*)d_in[9];
  const float* bf1     = (const float*)d_in[10];
  const float* Wf2     = (const float*)d_in[11];
  const float* bf2     = (const float*)d_in[12];
  const float* W2      = (const float*)d_in[13];
  const float* b2      = (const float*)d_in[14];
  const float* fc_w    = (const float*)d_in[15];
  const float* fc_b    = (const float*)d_in[16];
  float* out = (float*)d_out;

  char* ws = (char*)d_ws;
  size_t o = 0;
  auto alloc = [&](size_t bytes) {
    void* p = ws + o;
    o += (bytes + 255) & ~(size_t)255;
    return p;
  };
  char*     tabQ   = (char*)alloc(sizeof(char) * (size_t)LL * TTP * HH);
  float*    tabS   = (float*)alloc(sizeof(float) * (size_t)LL * TTP);
  ushort_t* xb     = (ushort_t*)alloc(sizeof(ushort_t) * (size_t)NN * FF);
  ushort_t* wt     = (ushort_t*)alloc(sizeof(ushort_t) * 8 * HH * HH);
  char*     q8a    = (char*)alloc(sizeof(char) * (size_t)NN * HH);
  char*     q8b    = (char*)alloc(sizeof(char) * (size_t)NN * HH);
  float*    scla   = (float*)alloc(sizeof(float) * (size_t)NN);
  float*    sclb   = (float*)alloc(sizeof(float) * (size_t)NN);
  ushort_t* hbuf   = (ushort_t*)alloc(sizeof(ushort_t) * (size_t)NN * HH);
  int*      bcnt   = (int*)alloc(sizeof(int) * NN);
  uint_t*   epad   = (uint_t*)alloc(sizeof(uint_t) * (size_t)NN * BD);
  uint_t*   seg    = (uint_t*)alloc(sizeof(uint_t) * (size_t)2 * 8 * ABLK * SEGC);
  int*      segcnt = (int*)alloc(sizeof(int) * 8 * ABLK);
  float*    gsum   = (float*)alloc(sizeof(float) * GG * HH);
  int*      gcnt   = (int*)alloc(sizeof(int) * GG);

  const int prepBlocks = PB_CVTW + PB_TAB + PB_CVTX + PB_PART + 1;  // 4222
  prep<<<prepBlocks, 256, 0, stream>>>(x, xb, W1_0, W1_rest, W2, wt,
                                       Wf1, bf1, Wf2, bf2, tabQ, tabS,
                                       edst, esrc, edist, seg, segcnt, bcnt,
                                       gid, gcnt, gsum);
  scatter_gemm1<<<SCB + GEMMB, 256, 0, stream>>>(seg, segcnt, bcnt, epad,
                                                 xb, wt, b1_0, q8a, scla);

  const char* pIn = q8a;
  const float* sIn = scla;
  char* pOut = q8b;
  float* sOut = sclb;
  for (int l = 0; l < LL; ++l) {
    int last = (l == LL - 1);
    fused_layer<<<GEMMB, 512, 0, stream>>>(
        pIn, sIn, tabQ + (size_t)l * TTP * HH, tabS + (size_t)l * TTP,
        epad, bcnt,
        wt + (size_t)(4 + l) * HH * HH, b2 + (size_t)l * HH,
        last ? nullptr : (wt + (size_t)(1 + l) * HH * HH),
        last ? nullptr : (b1_rest + (size_t)l * HH),
        pOut, sOut, hbuf, last);
    const char* tp = pIn; pIn = pOut; pOut = (char*)tp;
    const float* ts = sIn; sIn = sOut; sOut = (float*)ts;
  }

  pool_kernel<<<(NN + 127) / 128, 128, 0, stream>>>(hbuf, gid, gsum);
  final_kernel<<<GG, 128, 0, stream>>>(gsum, gcnt, fc_w, fc_b, out);
}

// Round 9
// 407.531 us; speedup vs baseline: 1.3563x; 1.0720x over previous
//
#include <hip/hip_runtime.h>
#include <math.h>

#define NN 50000
#define EE 800000
#define FF 64
#define HH 128
#define LL 4
#define GG 64
#define CC 10
#define TT 512     // table points per layer
#define TTP 513    // +1 zero row at index 0 (sentinel); real rows 1..512
#define BD 64      // padded bucket capacity per dst
#define ABLK 1024  // phase-A part blocks
#define EPB 782    // edges per phase-A block
#define SEGC 192   // per (block,region) segment capacity
#define SUBB 96    // phase-B sub-blocks per region
#define SRW 6250   // dst region width (NN/8)

// prep kernel block ranges
#define PB_CVTW 8
#define PB_TAB ((TT / 16) * LL)      // 128
#define PB_CVTX (NN * FF / 4 / 256)  // 3125
#define PB_PART ABLK

#define SCB (8 * SUBB)   // 768 scatter blocks in the combined dispatch
#define GEMMB (NN / 16)  // 3125 gemm tiles

typedef unsigned short ushort_t;
typedef unsigned int uint_t;
typedef unsigned long long u64_t;

typedef short s8v __attribute__((ext_vector_type(8)));
typedef float f32x4 __attribute__((ext_vector_type(4)));

__device__ inline ushort_t f2bf(float f) {
  uint_t u = __float_as_uint(f);
  uint_t r = (u + 0x7FFFu + ((u >> 16) & 1u)) >> 16;
  return (ushort_t)r;
}
__device__ inline float bf1f(ushort_t v) { return __uint_as_float(((uint_t)v) << 16); }

// f16 helpers: conversions lower to v_cvt_f16_f32 / v_cvt_f32_f16; the
// (float)h * (float)h + f32acc pattern lowers to v_fma_mix_f32 (no unpack).
__device__ inline ushort_t f2h(float f) {
  union { _Float16 h[2]; ushort_t us[2]; } c;
  c.h[0] = (_Float16)f;
  return c.us[0];
}
__device__ inline float h_lo(uint_t u) {
  union { uint_t w; _Float16 h[2]; } c; c.w = u; return (float)c.h[0];
}
__device__ inline float h_hi(uint_t u) {
  union { uint_t w; _Float16 h[2]; } c; c.w = u; return (float)c.h[1];
}

// ---------------- fused prep: cvt_w | build_tables | cvt_x | part_edges | gcnt+gsum ----------------
__global__ __launch_bounds__(256) void prep(
    const float* __restrict__ x, ushort_t* __restrict__ xb,
    const float* __restrict__ W1_0, const float* __restrict__ W1_rest,
    const float* __restrict__ W2, ushort_t* __restrict__ wt,
    const float* __restrict__ Wf1, const float* __restrict__ bf1,
    const float* __restrict__ Wf2, const float* __restrict__ bf2,
    ushort_t* __restrict__ tables,
    const int* __restrict__ dst, const int* __restrict__ src,
    const float* __restrict__ dist,
    uint_t* __restrict__ seg, int* __restrict__ segcnt, int* __restrict__ bcnt,
    const int* __restrict__ gid, int* __restrict__ gcnt, float* __restrict__ gsum) {
  __shared__ float rbf[16][HH];
  __shared__ float hid[16][HH];
  __shared__ int lcnt[8];
  int tid = threadIdx.x;
  int b = blockIdx.x;

  if (b < PB_CVTW) {
    int mid = b;
    const float* srcm; int K;
    if (mid == 0) { srcm = W1_0; K = FF; }
    else if (mid < 4) { srcm = W1_rest + (size_t)(mid - 1) * HH * HH; K = HH; }
    else { srcm = W2 + (size_t)(mid - 4) * HH * HH; K = HH; }
    ushort_t* dstm = wt + (size_t)mid * HH * HH;
    for (int idx = tid; idx < K * HH; idx += 256) {
      int k = idx >> 7, n = idx & 127;
      dstm[n * K + k] = f2bf(srcm[idx]);
    }
  } else if (b < PB_CVTW + PB_TAB) {
    int bb = b - PB_CVTW;
    int l = bb & 3;
    int tb = (bb >> 2) * 16;
    int j = tid & 127;
    float c = j * (1.0f / (HH - 1));
#pragma unroll
    for (int tt2 = 0; tt2 < 16; ++tt2) {
      float d = (tb + tt2) * (1.0f / (TT - 1));
      float dd = d - c;
      rbf[tt2][j] = expf(-10.0f * dd * dd);
    }
    __syncthreads();
    const float* W1f = Wf1 + (size_t)l * HH * HH;
    float s[16];
    float bb1 = bf1[l * HH + j];
#pragma unroll
    for (int tt2 = 0; tt2 < 16; ++tt2) s[tt2] = bb1;
    for (int k = 0; k < HH; ++k) {
      float wk = W1f[(size_t)k * HH + j];
#pragma unroll
      for (int tt2 = 0; tt2 < 16; ++tt2) s[tt2] += rbf[tt2][k] * wk;
    }
#pragma unroll
    for (int tt2 = 0; tt2 < 16; ++tt2)
      hid[tt2][j] = fmaxf(s[tt2], 0.f) + log1pf(expf(-fabsf(s[tt2]))) - 0.6931472f;
    __syncthreads();
    const float* W2f = Wf2 + (size_t)l * HH * HH;
    float bb2 = bf2[l * HH + j];
#pragma unroll
    for (int tt2 = 0; tt2 < 16; ++tt2) s[tt2] = bb2;
    for (int k = 0; k < HH; ++k) {
      float wk = W2f[(size_t)k * HH + j];
#pragma unroll
      for (int tt2 = 0; tt2 < 16; ++tt2) s[tt2] += hid[tt2][k] * wk;
    }
    if (tid < 128) {
      // rows shifted by +1: row 0 of each layer's table is the zero sentinel row
#pragma unroll
      for (int tt2 = 0; tt2 < 16; ++tt2)
        tables[((size_t)l * TTP + 1 + tb + tt2) * HH + j] = f2h(s[tt2]);
    }
  } else if (b < PB_CVTW + PB_TAB + PB_CVTX) {
    int i = (b - PB_CVTW - PB_TAB) * 256 + tid;
    const float4* x4 = (const float4*)x;
    float4 v = x4[i];
    union { ushort_t us[4]; u64_t u; } pk;
    pk.us[0] = f2bf(v.x); pk.us[1] = f2bf(v.y); pk.us[2] = f2bf(v.z); pk.us[3] = f2bf(v.w);
    *(u64_t*)&xb[i * 4] = pk.u;
  } else if (b < PB_CVTW + PB_TAB + PB_CVTX + PB_PART) {
    int pb = b - PB_CVTW - PB_TAB - PB_CVTX;
    if (tid < 8) lcnt[tid] = 0;
    int z = pb * 49 + tid;
    if (tid < 49 && z < NN) bcnt[z] = 0;
    __syncthreads();
    int e0 = pb * EPB;
    int e1 = min(e0 + EPB, EE);
    for (int e = e0 + tid; e < e1; e += 256) {
      int d = __builtin_nontemporal_load(dst + e);
      int s = __builtin_nontemporal_load(src + e);
      float di = __builtin_nontemporal_load(dist + e);
      float u = di * (float)(TT - 1);
      int t0 = (int)(fminf(fmaxf(u, 0.f), (float)(TT - 1)) + 0.5f);
      if (t0 > TT - 1) t0 = TT - 1;
      int r = d / SRW;
      int pos = atomicAdd(&lcnt[r], 1);
      if (pos < SEGC) {
        uint_t* sp = seg + (((size_t)(r << 10) + pb) * SEGC + pos) * 2;
        sp[0] = (uint_t)d;
        sp[1] = ((uint_t)s << 10) | (uint_t)(t0 + 1);
      }
    }
    __syncthreads();
    if (tid < 8) segcnt[(tid << 10) + pb] = min(lcnt[tid], SEGC);
  } else {
    for (int i = tid; i < GG * HH; i += 256) gsum[i] = 0.f;
    // zero sentinel row (row 0) of each layer's filter table
    for (int i = tid; i < LL * HH; i += 256)
      tables[(size_t)(i >> 7) * TTP * HH + (i & 127)] = 0;
    if (tid < GG) {
      int g = tid;
      int lo = 0, hi = NN;
      while (lo < hi) { int m = (lo + hi) >> 1; if (gid[m] < g) lo = m + 1; else hi = m; }
      int b0 = lo;
      lo = 0; hi = NN;
      int g1 = g + 1;
      while (lo < hi) { int m = (lo + hi) >> 1; if (gid[m] < g1) lo = m + 1; else hi = m; }
      gcnt[g] = lo - b0;
    }
  }
}

// ---------------- combined: per-region scatter (blocks 0..SCB) | gemm1 (rest) ----------------
// gemm1 epilogue writes f16 rows (layer-0 gather input).
__global__ __launch_bounds__(256) void scatter_gemm1(
    const uint_t* __restrict__ seg, const int* __restrict__ segcnt,
    int* __restrict__ bcnt, uint_t* __restrict__ epad,
    const ushort_t* __restrict__ xb, const ushort_t* __restrict__ wt,
    const float* __restrict__ b1_0, ushort_t* __restrict__ pbuf) {
  int tid = threadIdx.x;
  if (blockIdx.x < SCB) {
    int r = blockIdx.x & 7;
    int sub = blockIdx.x >> 3;
    for (int b = sub; b < ABLK; b += SUBB) {
      int cnt = segcnt[(r << 10) + b];
      const uint_t* sp = seg + ((size_t)(r << 10) + b) * SEGC * 2;
      for (int i = tid; i < cnt; i += 256) {
        uint_t ex = __builtin_nontemporal_load(sp + i * 2);
        uint_t ey = __builtin_nontemporal_load(sp + i * 2 + 1);
        int slot = atomicAdd(&bcnt[ex], 1);
        if (slot < BD) epad[(size_t)ex * BD + slot] = ey;
      }
    }
  } else {
    int tile = blockIdx.x - SCB;
    int lane = tid & 63, wave = tid >> 6, m = lane & 15, quad = lane >> 4;
    int rowbase = tile * 16, colbase = wave * 32;
    const ushort_t* arow = xb + (size_t)(rowbase + m) * FF;
    const ushort_t* brow0 = wt + (size_t)(colbase + m) * FF;
    const ushort_t* brow1 = wt + (size_t)(colbase + 16 + m) * FF;
    f32x4 acc0 = {0.f, 0.f, 0.f, 0.f};
    f32x4 acc1 = {0.f, 0.f, 0.f, 0.f};
    for (int kc = 0; kc < FF; kc += 32) {
      int k = kc + quad * 8;
      union { uint4 u; s8v v; } a, b0, b1;
      a.u  = *(const uint4*)(arow + k);
      b0.u = *(const uint4*)(brow0 + k);
      b1.u = *(const uint4*)(brow1 + k);
      acc0 = __builtin_amdgcn_mfma_f32_16x16x32_bf16(a.v, b0.v, acc0, 0, 0, 0);
      acc1 = __builtin_amdgcn_mfma_f32_16x16x32_bf16(a.v, b1.v, acc1, 0, 0, 0);
    }
    float bb0 = b1_0[colbase + m];
    float bb1 = b1_0[colbase + 16 + m];
#pragma unroll
    for (int reg = 0; reg < 4; ++reg) {
      int row = rowbase + quad * 4 + reg;
      pbuf[(size_t)row * HH + colbase + m] = f2h(acc0[reg] + bb0);
      pbuf[(size_t)row * HH + colbase + 16 + m] = f2h(acc1[reg] + bb1);
    }
  }
}

// ---------------- fused layer: pipelined f16 edge_agg + gemm2/gemm1 ----------------
// 512 threads / 8 waves, 2 nodes per wave. The gather loop is 2-DEEP SOFTWARE
// PIPELINED: batch c+1's 16 loads are issued BEFORE batch c is consumed, so the
// compiler emits counted vmcnt(16) waits (never drains to 0 inside the loop) and
// each wave keeps 32 gather loads in flight. Odd tails run on sentinel edges
// (edge word 0 -> zero filter row -> contributes exactly 0), so no guards.
#define ISSUE(PV, FV, CC)                                                     \
  do {                                                                        \
    _Pragma("unroll") for (int i_ = 0; i_ < 2; ++i_) {                        \
      _Pragma("unroll") for (int k_ = 0; k_ < 4; ++k_) {                      \
        uint_t e_ = (uint_t)__builtin_amdgcn_readlane((int)ed[i_],            \
                                                      (CC) * 4 + k_);         \
        PV[i_][k_] = pu[(size_t)(e_ >> 10) * 64 + lane];                      \
        FV[i_][k_] = tu[(size_t)(e_ & 1023u) * 64 + lane];                    \
      }                                                                       \
    }                                                                         \
  } while (0)

#define CONSUME(PV, FV)                                                       \
  do {                                                                        \
    _Pragma("unroll") for (int i_ = 0; i_ < 2; ++i_) {                        \
      _Pragma("unroll") for (int k_ = 0; k_ < 4; ++k_) {                      \
        ax[i_] += h_lo(PV[i_][k_]) * h_lo(FV[i_][k_]);                        \
        ay[i_] += h_hi(PV[i_][k_]) * h_hi(FV[i_][k_]);                        \
      }                                                                       \
    }                                                                         \
  } while (0)

__global__ __launch_bounds__(512) void fused_layer(
    const ushort_t* __restrict__ pIn, const ushort_t* __restrict__ table,
    const uint_t* __restrict__ epad, const int* __restrict__ bcnt,
    const ushort_t* __restrict__ WT2, const float* __restrict__ b2l,
    const ushort_t* __restrict__ WT1, const float* __restrict__ b1l,
    ushort_t* __restrict__ OUT, int last) {
  __shared__ ushort_t At[16 * 128];
  __shared__ ushort_t T[16 * 128];
  int tid = threadIdx.x;
  int lane = tid & 63;
  int wv = tid >> 6;  // 0..7
  int tile = blockIdx.x;
  const uint_t* pu = (const uint_t*)pIn;
  const uint_t* tu = (const uint_t*)table;

  int baseV = tile * 16 + wv * 2;
  uint_t ed[2];
  float ax[2], ay[2];
  int B = 0;
#pragma unroll
  for (int i = 0; i < 2; ++i) {
    int n = min(bcnt[baseV + i], BD);
    ed[i] = (lane < n) ? epad[(size_t)(baseV + i) * BD + lane] : 0u;
    B = max(B, (n + 3) >> 2);
    ax[i] = 0.f; ay[i] = 0.f;
  }
  int Be = (B + 1) & ~1;  // even # of batches; tail batches hit sentinel edges
  if (Be > 0) {
    uint_t pvA[2][4], fvA[2][4], pvB[2][4], fvB[2][4];
    ISSUE(pvA, fvA, 0);
    for (int c = 0; c < Be; c += 2) {
      ISSUE(pvB, fvB, c + 1);     // 16 more loads in flight before consuming A
      CONSUME(pvA, fvA);          // compiler waits vmcnt(16), not 0
      if (c + 2 < Be) ISSUE(pvA, fvA, c + 2);
      CONSUME(pvB, fvB);
    }
  }
#pragma unroll
  for (int i = 0; i < 2; ++i) {
    int r = wv * 2 + i;
    uint_t packed = (uint_t)f2bf(ax[i]) | ((uint_t)f2bf(ay[i]) << 16);
    ((uint_t*)At)[r * 64 + (((lane >> 2) ^ r) << 2) + (lane & 3)] = packed;
  }
  __syncthreads();
  int m = lane & 15, quad = lane >> 4;
  int rowbase = tile * 16, colbase = wv * 16;
  {
    const ushort_t* brow0 = WT2 + (size_t)(colbase + m) * HH;
    f32x4 acc0 = {0.f, 0.f, 0.f, 0.f};
    for (int kc = 0; kc < HH; kc += 32) {
      int k = kc + quad * 8;
      int g = k >> 3;
      union { uint4 u; s8v v; } a, b0;
      a.u = *(const uint4*)&At[m * 128 + ((g ^ m) << 3)];
      b0.u = *(const uint4*)(brow0 + k);
      acc0 = __builtin_amdgcn_mfma_f32_16x16x32_bf16(a.v, b0.v, acc0, 0, 0, 0);
    }
    float bb0 = b2l[colbase + m];
    if (last) {
#pragma unroll
      for (int reg = 0; reg < 4; ++reg) {
        int row = rowbase + quad * 4 + reg;
        OUT[(size_t)row * HH + colbase + m] = f2bf(fmaxf(acc0[reg] + bb0, 0.f));
      }
      return;
    }
#pragma unroll
    for (int reg = 0; reg < 4; ++reg) {
      int r = quad * 4 + reg;
      float v0 = fmaxf(acc0[reg] + bb0, 0.f);
      int c0 = colbase + m;
      T[r * 128 + (((c0 >> 3) ^ r) << 3) + (c0 & 7)] = f2bf(v0);
    }
  }
  __syncthreads();
  {
    const ushort_t* brow0 = WT1 + (size_t)(colbase + m) * HH;
    f32x4 acc0 = {0.f, 0.f, 0.f, 0.f};
    for (int kc = 0; kc < HH; kc += 32) {
      int k0 = kc + quad * 8;
      int g = k0 >> 3;
      union { uint4 u; s8v v; } a, b0;
      a.u = *(const uint4*)&T[m * 128 + ((g ^ m) << 3)];
      b0.u = *(const uint4*)(brow0 + k0);
      acc0 = __builtin_amdgcn_mfma_f32_16x16x32_bf16(a.v, b0.v, acc0, 0, 0, 0);
    }
    float bb0 = b1l[colbase + m];
#pragma unroll
    for (int reg = 0; reg < 4; ++reg) {
      int row = rowbase + quad * 4 + reg;
      OUT[(size_t)row * HH + colbase + m] = f2h(acc0[reg] + bb0);
    }
  }
}

// ---------------- pool: strip-parallel run-accumulate ----------------
__global__ __launch_bounds__(128) void pool_kernel(const ushort_t* __restrict__ h, const int* __restrict__ gid,
                                                   float* __restrict__ gsum) {
  int j = threadIdx.x;
  int i0 = blockIdx.x * 128;
  int i1 = min(i0 + 128, NN);
  if (i0 >= NN) return;
  float acc = 0.f;
  int gcur = gid[i0];
  for (int i = i0; i < i1; ++i) {
    int g = gid[i];
    if (g != gcur) {
      atomicAdd(&gsum[gcur * HH + j], acc);
      acc = 0.f;
      gcur = g;
    }
    acc += bf1f(h[(size_t)i * HH + j]);
  }
  atomicAdd(&gsum[gcur * HH + j], acc);
}

__global__ __launch_bounds__(128) void final_kernel(const float* __restrict__ gsum, const int* __restrict__ gcnt,
                                                    const float* __restrict__ fc_w, const float* __restrict__ fc_b,
                                                    float* __restrict__ out) {
  int g = blockIdx.x, j = threadIdx.x;
  __shared__ float pooled[HH];
  __shared__ float logits[CC];
  __shared__ float lse;
  float cnt = fmaxf((float)gcnt[g], 1.0f);
  pooled[j] = gsum[g * HH + j] / cnt;
  __syncthreads();
  if (j < CC) {
    float s = fc_b[j];
    for (int k = 0; k < HH; ++k) s += pooled[k] * fc_w[k * CC + j];
    logits[j] = s;
  }
  __syncthreads();
  if (j == 0) {
    float m = -1e30f;
    for (int c = 0; c < CC; ++c) m = fmaxf(m, logits[c]);
    float s = 0.f;
    for (int c = 0; c < CC; ++c) s += expf(logits[c] - m);
    lse = m + logf(s);
  }
  __syncthreads();
  if (j < CC) out[g * CC + j] = logits[j] - lse;
}

extern "C" void kernel_launch(void* const* d_in, const int* in_sizes, int n_in,
                              void* d_out, int out_size, void* d_ws, size_t ws_size,
                              hipStream_t stream) {
  const float* x       = (const float*)d_in[0];
  const float* edist   = (const float*)d_in[1];
  const int*   esrc    = (const int*)d_in[2];
  const int*   edst    = (const int*)d_in[3];
  const int*   gid     = (const int*)d_in[4];
  const float* W1_0    = (const float*)d_in[5];
  const float* b1_0    = (const float*)d_in[6];
  const float* W1_rest = (const float*)d_in[7];
  const float* b1_rest = (const float*)d_in[8];
  const float* Wf1     = (const float*)d_in[9];
  const float* bf1     = (const float*)d_in[10];
  const float* Wf2     = (const float*)d_in[11];
  const float* bf2     = (const float*)d_in[12];
  const float* W2      = (const float*)d_in[13];
  const float* b2      = (const float*)d_in[14];
  const float* fc_w    = (const float*)d_in[15];
  const float* fc_b    = (const float*)d_in[16];
  float* out = (float*)d_out;

  char* ws = (char*)d_ws;
  size_t o = 0;
  auto alloc = [&](size_t bytes) {
    void* p = ws + o;
    o += (bytes + 255) & ~(size_t)255;
    return p;
  };
  ushort_t* tables = (ushort_t*)alloc(sizeof(ushort_t) * (size_t)LL * TTP * HH);
  ushort_t* xb     = (ushort_t*)alloc(sizeof(ushort_t) * (size_t)NN * FF);
  ushort_t* wt     = (ushort_t*)alloc(sizeof(ushort_t) * 8 * HH * HH);
  ushort_t* pbuf   = (ushort_t*)alloc(sizeof(ushort_t) * (size_t)NN * HH);
  ushort_t* pbuf2  = (ushort_t*)alloc(sizeof(ushort_t) * (size_t)NN * HH);
  ushort_t* hbuf   = (ushort_t*)alloc(sizeof(ushort_t) * (size_t)NN * HH);
  int*      bcnt   = (int*)alloc(sizeof(int) * NN);
  uint_t*   epad   = (uint_t*)alloc(sizeof(uint_t) * (size_t)NN * BD);
  uint_t*   seg    = (uint_t*)alloc(sizeof(uint_t) * (size_t)2 * 8 * ABLK * SEGC);
  int*      segcnt = (int*)alloc(sizeof(int) * 8 * ABLK);
  float*    gsum   = (float*)alloc(sizeof(float) * GG * HH);
  int*      gcnt   = (int*)alloc(sizeof(int) * GG);

  const int prepBlocks = PB_CVTW + PB_TAB + PB_CVTX + PB_PART + 1;  // 4286
  prep<<<prepBlocks, 256, 0, stream>>>(x, xb, W1_0, W1_rest, W2, wt,
                                       Wf1, bf1, Wf2, bf2, tables,
                                       edst, esrc, edist, seg, segcnt, bcnt,
                                       gid, gcnt, gsum);
  scatter_gemm1<<<SCB + GEMMB, 256, 0, stream>>>(seg, segcnt, bcnt, epad,
                                                 xb, wt, b1_0, pbuf);

  ushort_t* pIn = pbuf;
  ushort_t* pOut = pbuf2;
  for (int l = 0; l < LL; ++l) {
    int last = (l == LL - 1);
    fused_layer<<<GEMMB, 512, 0, stream>>>(
        pIn, tables + (size_t)l * TTP * HH, epad, bcnt,
        wt + (size_t)(4 + l) * HH * HH, b2 + (size_t)l * HH,
        last ? nullptr : (wt + (size_t)(1 + l) * HH * HH),
        last ? nullptr : (b1_rest + (size_t)l * HH),
        last ? hbuf : pOut, last);
    ushort_t* tmp = pIn; pIn = pOut; pOut = tmp;
  }

  pool_kernel<<<(NN + 127) / 128, 128, 0, stream>>>(hbuf, gid, gsum);
  final_kernel<<<GG, 128, 0, stream>>>(gsum, gcnt, fc_w, fc_b, out);
}